// Round 14
// baseline (36596.140 us; speedup 1.0000x reference)
//
#include <hip/hip_runtime.h>
#include <math.h>

#define BB 256   // batch
#define TT 512   // encoder seq len
#define DD 64    // state dim
#define HH 512   // hidden dim
#define FF 32    // fc_seq_len (decoder steps)

__device__ __forceinline__ float sigmoidf_(float x) { return 1.0f / (1.0f + __expf(-x)); }

// ---------------- per-step GRU kernel, weight-slice stationary in LDS ----------------
// grid (64, 4): jt = blockIdx.x (8 j-cols), g = blockIdx.y (64 batch rows).
// 128 threads (2 waves): jj = tid>>4 (0..7), bi = tid&15; n=4 rows per thread
// (bi, +16, +32, +48). Per wave per k-pair: 3 w-reads (4 distinct jj, banks
// 4jj+k: conflict-free) + 4 h-reads (16 distinct bi, 2-way alias: free) = 7
// ds_read_b64 for 24 FMAs/lane -> 4032 LDS instrs/CU/step (r9: 5760).
// Launch boundary = the h(t) sync (in-kernel global sync costs 30-50us/step
// on 8 XCDs -- measured r8/r13; per-step launch gap is ~4-14us).
#define THRG 128
struct SmemW {
    float w[3][8][580];    // stride 580: 16B rows, banks 4jj+k -> conflict-free
    float hbuf[64][36];    // stride 36: 16B rows; h-read banks 4bi+k -> 2-way
};                         // 55680 + 9216 = 64896 B <= 64 KiB

// stage 64 rows x 32 cols of src (row stride rs): 4 float4/thread.
__device__ __forceinline__ void stage_issue(float4* pre, const float* __restrict__ src,
                                            int rs, int kc, int b0, int tid) {
    #pragma unroll
    for (int u = 0; u < 4; ++u) {
        const int idx = u * THRG + tid, r = idx >> 3, c4 = idx & 7;
        pre[u] = *(const float4*)&src[(b0 + r) * rs + kc + c4 * 4];
    }
}
__device__ __forceinline__ void stage_commit(float (*buf)[36], const float4* pre, int tid) {
    #pragma unroll
    for (int u = 0; u < 4; ++u) {
        const int idx = u * THRG + tid, r = idx >> 3, c4 = idx & 7;
        *(float4*)&buf[r][c4 * 4] = pre[u];
    }
}

// one 32-K chunk of the 3 gate GEMMs, n=4 rows
__device__ __forceinline__ void gru_chunk(const SmemW& g, int jj, int bi, int kb,
                                          float* ar, float* az, float* an) {
    #pragma unroll
    for (int kk = 0; kk < 32; kk += 2) {
        const float2 w0 = *(const float2*)&g.w[0][jj][kb + kk];
        const float2 w1 = *(const float2*)&g.w[1][jj][kb + kk];
        const float2 w2 = *(const float2*)&g.w[2][jj][kb + kk];
        #pragma unroll
        for (int q = 0; q < 4; ++q) {
            const float2 hv = *(const float2*)&g.hbuf[bi + 16 * q][kk];
            ar[q] = fmaf(hv.x, w0.x, ar[q]); ar[q] = fmaf(hv.y, w0.y, ar[q]);
            az[q] = fmaf(hv.x, w1.x, az[q]); az[q] = fmaf(hv.y, w1.y, az[q]);
            an[q] = fmaf(hv.x, w2.x, an[q]); an[q] = fmaf(hv.y, w2.y, an[q]);
        }
    }
}

__global__ __launch_bounds__(THRG) void gru_step_w(
    const float* __restrict__ x, int xs,             // [BB, *] rows at stride xs
    const float* __restrict__ h,                     // [BB, HH] or nullptr (zeros)
    const float* __restrict__ W_ih, const float* __restrict__ W_hh,
    const float* __restrict__ b_ih, const float* __restrict__ b_hh,
    float* __restrict__ hnew,                        // [BB, HH]
    float* __restrict__ h2, int h2s)                 // optional extra write (h_seq)
{
    __shared__ SmemW sm;
    const int tid = threadIdx.x;
    const int j0 = blockIdx.x * 8, b0 = blockIdx.y * 64;
    const int jj = tid >> 4, bi = tid & 15;
    const int j = j0 + jj;

    // ---- W slice -> LDS: 3 gates x 8 rows x 576 cols (cols<64 = W_ih) ----
    for (int i = tid; i < 3 * 8 * 576; i += THRG) {
        const int gg = i / 4608, rem = i - gg * 4608, r = rem / 576, k = rem - r * 576;
        sm.w[gg][r][k] = (k < DD) ? W_ih[(gg * HH + j0 + r) * DD + k]
                                  : W_hh[(gg * HH + j0 + r) * HH + (k - DD)];
    }
    const float br  = b_ih[j] + b_hh[j];
    const float bz  = b_ih[HH + j] + b_hh[HH + j];
    const float bin = b_ih[2 * HH + j];
    const float bhn = b_hh[2 * HH + j];

    float ar[4] = {0,0,0,0}, az[4] = {0,0,0,0}, ain[4] = {0,0,0,0}, ahn[4] = {0,0,0,0};
    float4 pre[4];

    // ---- x part: K 0..63 (weight cols 0..63) ----
    stage_issue(pre, x, xs, 0, b0, tid);
    stage_commit(sm.hbuf, pre, tid);
    __syncthreads();                                  // covers W load + chunk 0
    stage_issue(pre, x, xs, 32, b0, tid);
    gru_chunk(sm, jj, bi, 0, ar, az, ain);
    __syncthreads();
    stage_commit(sm.hbuf, pre, tid);
    __syncthreads();
    gru_chunk(sm, jj, bi, 32, ar, az, ain);
    __syncthreads();

    // ---- h part: K 0..511 (weight cols 64..575) ----
    if (h) {
        stage_issue(pre, h, HH, 0, b0, tid);
        stage_commit(sm.hbuf, pre, tid);
        __syncthreads();
        for (int c = 0; c < 16; ++c) {
            if (c < 15) stage_issue(pre, h, HH, 32 * (c + 1), b0, tid);
            gru_chunk(sm, jj, bi, 64 + 32 * c, ar, az, ahn);
            __syncthreads();
            if (c < 15) { stage_commit(sm.hbuf, pre, tid); __syncthreads(); }
        }
    }

    // ---- epilogue: n = tanh(i_n + r*h_n); h' = (1-z)n + z h ----
    #pragma unroll
    for (int q = 0; q < 4; ++q) {
        const int b = b0 + bi + 16 * q;
        const float r = sigmoidf_(ar[q] + br);
        const float z = sigmoidf_(az[q] + bz);
        const float hold = h ? h[b * HH + j] : 0.f;
        const float n = tanhf(ain[q] + bin + r * (ahn[q] + bhn));
        const float hn = (1.f - z) * n + z * hold;
        hnew[b * HH + j] = hn;
        if (h2) h2[b * h2s + j] = hn;
    }
}

// ---------------- fc kernels (round-3/9-verified) ----------------
struct SmemOld { float hs[16][34]; float ws[96][34]; };

__global__ __launch_bounds__(256) void fc1_relu(
    const float* __restrict__ h, const float* __restrict__ wsrc,
    const float* __restrict__ bias, float* __restrict__ out) {
    __shared__ SmemOld sm;
    float (*hs)[34] = sm.hs; float (*ws)[34] = sm.ws;
    const int tid = threadIdx.x;
    const int jj = tid & 31, bb = tid >> 5;
    const int j0 = blockIdx.x * 32, b0 = blockIdx.y * 16;
    float a0 = 0.f, a1 = 0.f;
    for (int kt = 0; kt < HH; kt += 32) {
        { const int r = tid >> 4, c2 = (tid & 15) * 2;
          *(float2*)&hs[r][c2] = *(const float2*)&h[(b0 + r) * HH + kt + c2]; }
        #pragma unroll
        for (int i = 0; i < 2; ++i) {
            const int idx = i * 256 + tid, r = idx >> 4, c2 = (idx & 15) * 2;
            *(float2*)&ws[r][c2] = *(const float2*)&wsrc[(j0 + r) * HH + kt + c2];
        }
        __syncthreads();
        #pragma unroll
        for (int k = 0; k < 32; k += 2) {
            const float2 h0 = *(const float2*)&hs[bb][k];
            const float2 h1 = *(const float2*)&hs[bb + 8][k];
            const float2 w0 = *(const float2*)&ws[jj][k];
            a0 = fmaf(h0.x, w0.x, a0); a0 = fmaf(h0.y, w0.y, a0);
            a1 = fmaf(h1.x, w0.x, a1); a1 = fmaf(h1.y, w0.y, a1);
        }
        __syncthreads();
    }
    const float b = bias[j0 + jj];
    out[(b0 + bb) * HH + j0 + jj]     = fmaxf(a0 + b, 0.f);
    out[(b0 + bb + 8) * HH + j0 + jj] = fmaxf(a1 + b, 0.f);
}

__global__ __launch_bounds__(256) void fc2_out(
    const float* __restrict__ a, const float* __restrict__ wsrc,
    const float* __restrict__ bias, float* __restrict__ s_buf,
    float* __restrict__ s_out, int s_stride) {
    __shared__ SmemOld sm;
    float (*as)[34] = sm.hs; float (*ws)[34] = sm.ws;
    const int tid = threadIdx.x;
    const int d = tid & 63, bb = tid >> 6;
    const int b0 = blockIdx.x * 4;
    float acc = 0.f;
    for (int kt = 0; kt < HH; kt += 32) {
        if (tid < 64) { const int r = tid >> 4, c2 = (tid & 15) * 2;
            *(float2*)&as[r][c2] = *(const float2*)&a[(b0 + r) * HH + kt + c2]; }
        #pragma unroll
        for (int i = 0; i < 4; ++i) {
            const int idx = i * 256 + tid, r = idx >> 4, c2 = (idx & 15) * 2;
            *(float2*)&ws[r][c2] = *(const float2*)&wsrc[r * HH + kt + c2];
        }
        __syncthreads();
        #pragma unroll
        for (int k = 0; k < 32; k += 2) {
            const float2 av = *(const float2*)&as[bb][k];
            const float2 wv = *(const float2*)&ws[d][k];
            acc = fmaf(av.x, wv.x, acc); acc = fmaf(av.y, wv.y, acc);
        }
        __syncthreads();
    }
    const float v = acc + bias[d];
    s_buf[(b0 + bb) * DD + d] = v;
    s_out[(b0 + bb) * s_stride + d] = v;
}

extern "C" void kernel_launch(void* const* d_in, const int* in_sizes, int n_in,
                              void* d_out, int out_size, void* d_ws, size_t ws_size,
                              hipStream_t stream) {
    const float* state_seq = (const float*)d_in[0];  // [256,512,64]
    const float* W_ih  = (const float*)d_in[1];      // [1536,64]
    const float* W_hh  = (const float*)d_in[2];      // [1536,512]
    const float* b_ih  = (const float*)d_in[3];
    const float* b_hh  = (const float*)d_in[4];
    const float* fc1_w = (const float*)d_in[5];      // [512,512]
    const float* fc1_b = (const float*)d_in[6];
    const float* fc2_w = (const float*)d_in[7];      // [64,512]
    const float* fc2_b = (const float*)d_in[8];

    float* out_s = (float*)d_out;                    // [256, 32, 64]
    float* out_h = out_s + BB * FF * DD;             // [256, 32, 512]

    float* hA   = (float*)d_ws;
    float* hB   = hA + BB * HH;
    float* aBuf = hB + BB * HH;
    float* sBuf = aBuf + BB * HH;

    const dim3 gruGrid(HH / 8, BB / 64);             // (64, 4)
    const dim3 gruBlk(THRG);

    // ---- encoder: 512 per-step launches (launch boundary = h sync) ----
    const float* hcur = nullptr;
    for (int t = 0; t < TT; ++t) {
        float* hout = (t & 1) ? hB : hA;
        float* hout2 = (t == TT - 1) ? out_h : nullptr;   // h_seq[:,0,:]
        gru_step_w<<<gruGrid, gruBlk, 0, stream>>>(state_seq + t * DD, TT * DD, hcur,
                                                   W_ih, W_hh, b_ih, b_hh,
                                                   hout, hout2, FF * HH);
        hcur = hout;
    }

    // ---- decoder: 32 fc_predicts, 31 GRU steps ----
    for (int t = 0; t < FF; ++t) {
        fc1_relu<<<dim3(HH / 32, BB / 16), dim3(256), 0, stream>>>(hcur, fc1_w, fc1_b, aBuf);
        fc2_out<<<dim3(BB / 4), dim3(256), 0, stream>>>(aBuf, fc2_w, fc2_b, sBuf,
                                                        out_s + t * DD, FF * DD);
        if (t < FF - 1) {
            float* hout = (hcur == hA) ? hB : hA;
            gru_step_w<<<gruGrid, gruBlk, 0, stream>>>(sBuf, DD, hcur,
                                                       W_ih, W_hh, b_ih, b_hh,
                                                       hout, out_h + (t + 1) * HH, FF * HH);
            hcur = hout;
        }
    }
}